// Round 9
// baseline (226.014 us; speedup 1.0000x reference)
//
#include <hip/hip_runtime.h>
#include <hip/hip_bf16.h>

typedef __hip_bfloat16 bf16;
typedef __attribute__((ext_vector_type(8))) short bf16x8;
typedef __attribute__((ext_vector_type(4))) float f32x4;

#define BATCH 4
#define CIN   512
#define HW    64
#define NPIX  4096
#define CALL  3072
#define NHEAD 128
#define EPS_LITE 1e-15f
#define BN_EPS   1e-5f

// Workspace (bytes), total ~138.2 MiB:
//   qkv_all (bf16): 0         .. 100663296
//   attT/xT (bf16): 100663296 .. 134217728   (xT aliases attT; dead before att writes)
//   part    (f32) : 134217728 .. 135397376
//   Wbf     (bf16): 135544832 .. 137117696
//   Pbf     (bf16): 137117696 .. 138166272

__device__ __forceinline__ short f2bf(float f) {
    __hip_bfloat16 h = __float2bfloat16(f);
    short s; __builtin_memcpy(&s, &h, 2); return s;
}
__device__ __forceinline__ float bfl(unsigned u) {
    unsigned v = u << 16; float f; __builtin_memcpy(&f, &v, 4); return f;
}
__device__ __forceinline__ float bfh(unsigned u) {
    unsigned v = u & 0xffff0000u; float f; __builtin_memcpy(&f, &v, 4); return f;
}
__device__ __forceinline__ unsigned packbf(float a, float b) {
    return (unsigned)(unsigned short)f2bf(a) | ((unsigned)(unsigned short)f2bf(b) << 16);
}
__device__ __forceinline__ void gll16(const void* gsrc, void* ldst) {
    __builtin_amdgcn_global_load_lds(
        (const __attribute__((address_space(1))) unsigned int*)gsrc,
        (__attribute__((address_space(3))) unsigned int*)ldst, 16, 0, 0);
}

// ---------------------------------------------------------------------------
// K0: merged pre-pass — cvtx (bid<2048) + cvtw (bid>=2048). 3328 blocks.
__global__ __launch_bounds__(256) void k_cvt(const float* __restrict__ x,
                                             const float* __restrict__ wq,
                                             const float* __restrict__ wk,
                                             const float* __restrict__ wv,
                                             const float* __restrict__ pj,
                                             bf16* __restrict__ xT,
                                             bf16* __restrict__ Wbf,
                                             bf16* __restrict__ Pbf) {
    __shared__ short lds[64][72];
    const int bid = blockIdx.x;
    const int t   = threadIdx.x;

    if (bid < 2048) {   // ---- cvtx: x [b][512][4096] f32 -> xT [b][px][512] bf16
        const int px0 = (bid & 63) * 64;
        const int k0  = ((bid >> 6) & 7) * 64;
        const int b   = bid >> 9;

        const int pr = t & 15, rr = t >> 4;
#pragma unroll
        for (int it = 0; it < 4; ++it) {
            const int row = it * 16 + rr;
            f32x4 v = *(const f32x4*)(x + (size_t)(b * CIN + k0 + row) * NPIX + px0 + pr * 4);
#pragma unroll
            for (int i = 0; i < 4; ++i) lds[pr * 4 + i][row] = f2bf(v[i]);
        }
        __syncthreads();

        const int px = t >> 2, kc = t & 3;
        uint4 u0 = *(const uint4*)&lds[px][kc * 16];
        uint4 u1 = *(const uint4*)&lds[px][kc * 16 + 8];
        bf16* dst = xT + ((size_t)b * NPIX + px0 + px) * 512 + k0 + kc * 16;
        *(uint4*)dst = u0;
        *(uint4*)(dst + 8) = u1;
    } else {            // ---- cvtw: weights -> bf16
        const int e = ((bid - 2048) * 256 + t) * 4;
        const float* s; bf16* dst;
        if (e < 786432) {
            int o;
            if (e < 262144)      { s = wq; o = e; }
            else if (e < 524288) { s = wk; o = e - 262144; }
            else                 { s = wv; o = e - 524288; }
            f32x4 v = *(const f32x4*)(s + o);
            dst = Wbf + e;
            *(ushort2*)dst = make_ushort2((unsigned short)f2bf(v[0]), (unsigned short)f2bf(v[1]));
            *(ushort2*)(dst + 2) = make_ushort2((unsigned short)f2bf(v[2]), (unsigned short)f2bf(v[3]));
        } else {
            const int o = e - 786432;
            f32x4 v = *(const f32x4*)(pj + o);
            dst = Pbf + o;
            *(ushort2*)dst = make_ushort2((unsigned short)f2bf(v[0]), (unsigned short)f2bf(v[1]));
            *(ushort2*)(dst + 2) = make_ushort2((unsigned short)f2bf(v[2]), (unsigned short)f2bf(v[3]));
        }
    }
}

// ---------------------------------------------------------------------------
// MFMA GEMM v3 (gll16 both operands). (unchanged)
template<int KD, int MT, bool PROJ>
__global__ __launch_bounds__(256) void k_gemm3(
        const bf16* __restrict__ Xt,
        const bf16* __restrict__ Wb,
        bf16* __restrict__ Obf,
        const float* __restrict__ gm, const float* __restrict__ bt,
        const float* __restrict__ mu, const float* __restrict__ va,
        const float* __restrict__ resid, float* __restrict__ Of)
{
    constexpr int NT = KD / 32;
    constexpr int MS = MT / 32;
    constexpr int AG = MT / 64;
    __shared__ short Ald[2][MT * 32];
    __shared__ short Bld[2][128 * 32];

    const int t    = threadIdx.x;
    const int lane = t & 63;
    const int w    = t >> 6;
    const int wm   = w >> 1, wn = w & 1;
    const int n0   = blockIdx.x * 128;
    const int c0   = blockIdx.y * MT;
    const int b    = blockIdx.z;

    const bf16* abase = Wb + (size_t)(c0 + w * (MT / 4) + (lane >> 2)) * KD + (lane & 3) * 8;
    const bf16* bbase = Xt + ((size_t)b * NPIX + n0 + w * 32 + (lane >> 2)) * KD + (lane & 3) * 8;

    auto stage = [&](int s, int buf) {
#pragma unroll
        for (int q = 0; q < AG; ++q)
            gll16(abase + (size_t)q * 16 * KD + s * 32,
                  &Ald[buf][(w * (MT / 4) + q * 16) * 32]);
#pragma unroll
        for (int q = 0; q < 2; ++q)
            gll16(bbase + (size_t)q * 16 * KD + s * 32,
                  &Bld[buf][(w * 32 + q * 16) * 32]);
    };

    f32x4 acc[MS][4];
#pragma unroll
    for (int ms = 0; ms < MS; ++ms)
#pragma unroll
        for (int ns = 0; ns < 4; ++ns)
#pragma unroll
            for (int j = 0; j < 4; ++j) acc[ms][ns][j] = 0.f;

    stage(0, 0);
    __syncthreads();

    const int l15 = lane & 15, l4 = lane >> 4;
    for (int s = 0; s < NT; ++s) {
        const int cur = s & 1;
        if (s + 1 < NT) stage(s + 1, cur ^ 1);

        bf16x8 af[MS], bv[4];
#pragma unroll
        for (int ms = 0; ms < MS; ++ms)
            af[ms] = *(const bf16x8*)&Ald[cur][(wm * (MT / 2) + ms * 16 + l15) * 32 + l4 * 8];
#pragma unroll
        for (int ns = 0; ns < 4; ++ns)
            bv[ns] = *(const bf16x8*)&Bld[cur][(wn * 64 + ns * 16 + l15) * 32 + l4 * 8];
#pragma unroll
        for (int ms = 0; ms < MS; ++ms)
#pragma unroll
            for (int ns = 0; ns < 4; ++ns)
                acc[ms][ns] = __builtin_amdgcn_mfma_f32_16x16x32_bf16(
                    af[ms], bv[ns], acc[ms][ns], 0, 0, 0);

        __syncthreads();
    }

    if (!PROJ) {
#pragma unroll
        for (int ms = 0; ms < MS; ++ms) {
            const int crow = c0 + wm * (MT / 2) + ms * 16 + l4 * 4;
#pragma unroll
            for (int ns = 0; ns < 4; ++ns) {
                const int ncol = n0 + wn * 64 + ns * 16 + l15;
#pragma unroll
                for (int j = 0; j < 4; ++j) {
                    bf16 h; short sv = f2bf(acc[ms][ns][j]);
                    __builtin_memcpy(&h, &sv, 2);
                    Obf[((size_t)b * CALL + crow + j) * NPIX + ncol] = h;
                }
            }
        }
    } else {
#pragma unroll
        for (int ms = 0; ms < MS; ++ms) {
            const int crow = c0 + wm * (MT / 2) + ms * 16 + l4 * 4;
#pragma unroll
            for (int j = 0; j < 4; ++j) {
                const int o = crow + j;
                const float inv = gm[o] / sqrtf(va[o] + BN_EPS);
                const float sh  = bt[o] - mu[o] * inv;
#pragma unroll
                for (int ns = 0; ns < 4; ++ns) {
                    const int ncol = n0 + wn * 64 + ns * 16 + l15;
                    const size_t idx = ((size_t)b * 512 + o) * NPIX + ncol;
                    Of[idx] = acc[ms][ns][j] * inv + sh + resid[idx];
                }
            }
        }
    }
}

// ---------------------------------------------------------------------------
// Device bodies (byte-identical logic to R8 kernels).
#define DW_ICS 1608
#define DW_DCS 1032

__device__ __forceinline__ void dwpw_body(const float* __restrict__ dwk,
                                          const float* __restrict__ pwk,
                                          bf16* __restrict__ qkv_all,
                                          short* slds,
                                          int ytile, int g, int b) {
    const int t  = threadIdx.x;
    const int y0 = ytile * 16;

    const bf16* src = qkv_all + ((size_t)b * CALL + g * 8) * NPIX;
#pragma unroll
    for (int i = 0; i < 7; ++i) {
        const int v = i * 256 + t;
        if (v < 1600) {
            const int ch  = v / 200;
            const int rem = v % 200;
            const int row = rem / 10;
            const int seg = rem % 10;
            const int grow = y0 + row - 2;
            uint4 val = make_uint4(0u, 0u, 0u, 0u);
            if (seg >= 1 && seg <= 8 && grow >= 0 && grow < HW)
                val = *(const uint4*)(src + (size_t)ch * NPIX + grow * HW + (seg - 1) * 8);
            *(uint4*)&slds[ch * DW_ICS + row * 80 + seg * 8] = val;
        }
    }

    const int lane = t & 63;
    const int w    = t >> 6;
    const int xb   = lane & 7;
    const int ch   = lane >> 3;
    const int x0   = xb * 8;

    float kc[25];
    {
        const float* kp = dwk + (size_t)(g * 8 + ch) * 25;
#pragma unroll
        for (int i = 0; i < 25; ++i) kc[i] = kp[i];
    }
    __syncthreads();

    float A[5][12];
    const short* cb = &slds[ch * DW_ICS + x0];

    auto loadrow = [&](int L, float* f) {
        const short* rp = cb + L * 80;
        uint2 lo = *(const uint2*)(rp + 4);
        uint4 md = *(const uint4*)(rp + 8);
        uint2 hi = *(const uint2*)(rp + 16);
        f[0]  = bfl(lo.y); f[1]  = bfh(lo.y);
        f[2]  = bfl(md.x); f[3]  = bfh(md.x);
        f[4]  = bfl(md.y); f[5]  = bfh(md.y);
        f[6]  = bfl(md.z); f[7]  = bfh(md.z);
        f[8]  = bfl(md.w); f[9]  = bfh(md.w);
        f[10] = bfl(hi.x); f[11] = bfh(hi.x);
    };

    const int r0 = w * 4;
    loadrow(r0 + 0, A[0]);
    loadrow(r0 + 1, A[1]);
    loadrow(r0 + 2, A[2]);
    loadrow(r0 + 3, A[3]);

    uint4 pk[4];
#pragma unroll
    for (int ri = 0; ri < 4; ++ri) {
        loadrow(r0 + ri + 4, A[(ri + 4) % 5]);
        float acc[8];
#pragma unroll
        for (int i = 0; i < 8; ++i) acc[i] = 0.f;
#pragma unroll
        for (int dy = 0; dy < 5; ++dy) {
            const float* Ar = A[(ri + dy) % 5];
#pragma unroll
            for (int dx = 0; dx < 5; ++dx) {
                const float kv = kc[dy * 5 + dx];
#pragma unroll
                for (int i = 0; i < 8; ++i)
                    acc[i] += Ar[i + dx] * kv;
            }
        }
        pk[ri].x = packbf(acc[0], acc[1]);
        pk[ri].y = packbf(acc[2], acc[3]);
        pk[ri].z = packbf(acc[4], acc[5]);
        pk[ri].w = packbf(acc[6], acc[7]);
    }
    __syncthreads();

#pragma unroll
    for (int ri = 0; ri < 4; ++ri)
        *(uint4*)&slds[ch * DW_DCS + (r0 + ri) * 64 + x0] = pk[ri];
    __syncthreads();

    const float* pwb = pwk + (size_t)g * 64;
#pragma unroll
    for (int it = 0; it < 2; ++it) {
        const int p2 = (it * 256 + t) * 2;
        float v0[8], v1[8];
#pragma unroll
        for (int ci = 0; ci < 8; ++ci) {
            const unsigned u = *(const unsigned*)&slds[ci * DW_DCS + p2];
            v0[ci] = bfl(u); v1[ci] = bfh(u);
        }
        bf16* op = qkv_all + ((size_t)b * CALL + 1536 + g * 8) * NPIX + y0 * HW + p2;
#pragma unroll
        for (int o = 0; o < 8; ++o) {
            float s0 = 0.f, s1 = 0.f;
#pragma unroll
            for (int ci = 0; ci < 8; ++ci) {
                const float wv = pwb[o * 8 + ci];
                s0 += wv * v0[ci]; s1 += wv * v1[ci];
            }
            *(unsigned*)(op + (size_t)o * NPIX) = packbf(s0, s1);
        }
    }
}

__device__ __forceinline__ void scores_body(const bf16* __restrict__ qkv_all,
                                            float* __restrict__ part,
                                            int ns, int h, int b) {
    const int lane = threadIdx.x & 63;
    const bf16* base = qkv_all + ((size_t)b * CALL + h * 24) * NPIX;

    float acc[72];
#pragma unroll
    for (int i = 0; i < 72; ++i) acc[i] = 0.f;

    for (int it = 0; it < 4; ++it) {
        const int n = ns * 512 + it * 128 + lane * 2;
        const bf16* p = base + n;
        float k0[8], k1[8], v0[8], v1[8];
#pragma unroll
        for (int e = 0; e < 8; ++e) {
            const unsigned u = *(const unsigned*)&p[(size_t)(8 + e) * NPIX];
            k0[e] = fmaxf(bfl(u), 0.f); k1[e] = fmaxf(bfh(u), 0.f);
        }
#pragma unroll
        for (int d = 0; d < 8; ++d) {
            const unsigned u = *(const unsigned*)&p[(size_t)(16 + d) * NPIX];
            v0[d] = bfl(u); v1[d] = bfh(u);
        }
#pragma unroll
        for (int d = 0; d < 9; ++d) {
            const float vd0 = (d < 8) ? v0[d] : 1.f;
            const float vd1 = (d < 8) ? v1[d] : 1.f;
#pragma unroll
            for (int e = 0; e < 8; ++e)
                acc[d * 8 + e] += vd0 * k0[e] + vd1 * k1[e];
        }
    }

    const int bh = b * NHEAD + h;
#pragma unroll
    for (int i = 0; i < 72; ++i) {
        float v = acc[i];
        for (int off = 32; off; off >>= 1) v += __shfl_xor(v, off, 64);
        if (lane == 0) part[((size_t)bh * 72 + i) * 8 + ns] = v;
    }
}

__device__ __forceinline__ void att_body(const bf16* __restrict__ qkv_all,
                                         const float* __restrict__ part,
                                         bf16* __restrict__ attT,
                                         float* sc,
                                         int xt, int h, int b) {
    const int t  = threadIdx.x;
    const int bh = b * NHEAD + h;

    if (t < 72) {
        float s = 0.f;
#pragma unroll
        for (int nss = 0; nss < 8; ++nss) s += part[((size_t)bh * 72 + t) * 8 + nss];
        sc[t] = s;
    }
    __syncthreads();

    const int px = xt * 256 + t;
    const bf16* qb = qkv_all + ((size_t)b * CALL + h * 24) * NPIX + px;
    float q[8];
#pragma unroll
    for (int e = 0; e < 8; ++e)
        q[e] = fmaxf(__bfloat162float(qb[(size_t)e * NPIX]), 0.f);

    float num[9];
#pragma unroll
    for (int d = 0; d < 9; ++d) {
        float s = 0.f;
#pragma unroll
        for (int e = 0; e < 8; ++e) s += sc[d * 8 + e] * q[e];
        num[d] = s;
    }
    const float inv = 1.f / (num[8] + EPS_LITE);
    uint4 pk;
    pk.x = packbf(num[0] * inv, num[1] * inv);
    pk.y = packbf(num[2] * inv, num[3] * inv);
    pk.z = packbf(num[4] * inv, num[5] * inv);
    pk.w = packbf(num[6] * inv, num[7] * inv);
    *(uint4*)(attT + ((size_t)b * NPIX + px) * 1024 + h * 8) = pk;
}

// ---------------------------------------------------------------------------
// Fuse1: scores heads 0-63 (bid<512) + dwpw (bid>=512). 3584 blocks @256.
__global__ __launch_bounds__(256, 4) void k_fuse1(const float* __restrict__ dwk,
                                                  const float* __restrict__ pwk,
                                                  bf16* __restrict__ qkv_all,
                                                  float* __restrict__ part) {
    __shared__ short slds[8 * DW_ICS];
    const int bid = blockIdx.x;
    if (bid < 512) {
        const int ns = bid & 7, hg = (bid >> 3) & 15, b = bid >> 7;
        const int h  = hg * 4 + (threadIdx.x >> 6);
        scores_body(qkv_all, part, ns, h, b);
    } else {
        const int db = bid - 512;
        const int ytile = db & 3, g = (db >> 2) % 192, b = db / 768;
        dwpw_body(dwk, pwk, qkv_all, slds, ytile, g, b);
    }
}

// Fuse2: scores heads 64-127 (bid<512) + att heads 0-63 (bid>=512). 4608 blocks.
__global__ __launch_bounds__(256, 4) void k_fuse2(const bf16* __restrict__ qkv_all,
                                                  float* __restrict__ part,
                                                  bf16* __restrict__ attT) {
    __shared__ float sc[72];
    const int bid = blockIdx.x;
    if (bid < 512) {
        const int ns = bid & 7, hg = (bid >> 3) & 15, b = bid >> 7;
        const int h  = 64 + hg * 4 + (threadIdx.x >> 6);
        scores_body(qkv_all, part, ns, h, b);
    } else {
        const int ab = bid - 512;
        const int xt = ab & 15, h = (ab >> 4) & 63, b = ab >> 10;
        att_body(qkv_all, part, attT, sc, xt, h, b);
    }
}

// att heads 64-127. grid (16,64,4) @256.
__global__ __launch_bounds__(256) void k_att_hi(const bf16* __restrict__ qkv_all,
                                                const float* __restrict__ part,
                                                bf16* __restrict__ attT) {
    __shared__ float sc[72];
    att_body(qkv_all, part, attT, sc, blockIdx.x, blockIdx.y + 64, blockIdx.z);
}

// ---------------------------------------------------------------------------
extern "C" void kernel_launch(void* const* d_in, const int* in_sizes, int n_in,
                              void* d_out, int out_size, void* d_ws, size_t ws_size,
                              hipStream_t stream) {
    const float* x   = (const float*)d_in[0];
    const float* wq  = (const float*)d_in[1];
    const float* wk  = (const float*)d_in[2];
    const float* wv  = (const float*)d_in[3];
    const float* dwk = (const float*)d_in[4];
    const float* pwk = (const float*)d_in[5];
    const float* pj  = (const float*)d_in[6];
    const float* gm  = (const float*)d_in[7];
    const float* bt  = (const float*)d_in[8];
    const float* mu  = (const float*)d_in[9];
    const float* va  = (const float*)d_in[10];
    float* out = (float*)d_out;

    char* ws = (char*)d_ws;
    bf16*  qkv_all = (bf16*)(ws);
    bf16*  attT    = (bf16*)(ws + 100663296);
    bf16*  xT      = (bf16*)(ws + 100663296);   // aliases attT; dead before att writes
    float* part    = (float*)(ws + 134217728);
    bf16*  Wbf     = (bf16*)(ws + 135544832);
    bf16*  Pbf     = (bf16*)(ws + 137117696);

    k_cvt<<<dim3(3328), 256, 0, stream>>>(x, wq, wk, wv, pj, xT, Wbf, Pbf);
    // QKV: M=1536, K=512
    k_gemm3<512, 128, false><<<dim3(32, 12, BATCH), 256, 0, stream>>>(
        xT, Wbf, qkv_all, nullptr, nullptr, nullptr, nullptr, nullptr, nullptr);
    k_fuse1 <<<dim3(3584), 256, 0, stream>>>(dwk, pwk, qkv_all, part);
    k_fuse2 <<<dim3(4608), 256, 0, stream>>>(qkv_all, part, attT);
    k_att_hi<<<dim3(16, 64, BATCH), 256, 0, stream>>>(qkv_all, part, attT);
    // Proj: M=512, K=1024, + BN + residual
    k_gemm3<1024, 64, true><<<dim3(32, 8, BATCH), 256, 0, stream>>>(
        attT, Pbf, nullptr, gm, bt, mu, va, x, out);
}

// Round 10
// 184.433 us; speedup vs baseline: 1.2255x; 1.2255x over previous
//
#include <hip/hip_runtime.h>
#include <hip/hip_bf16.h>

typedef __hip_bfloat16 bf16;
typedef __attribute__((ext_vector_type(8))) short bf16x8;
typedef __attribute__((ext_vector_type(4))) float f32x4;

#define BATCH 4
#define CIN   512
#define HW    64
#define NPIX  4096
#define CALL  3072
#define NHEAD 128
#define EPS_LITE 1e-15f
#define BN_EPS   1e-5f

// Workspace (bytes), total ~138.2 MiB:
//   qkv_all (bf16): 0         .. 100663296
//   attT/xT (bf16): 100663296 .. 134217728   (xT aliases attT; dead before att writes)
//   part    (f32) : 134217728 .. 135397376
//   Wbf     (bf16): 135544832 .. 137117696
//   Pbf     (bf16): 137117696 .. 138166272

__device__ __forceinline__ short f2bf(float f) {
    __hip_bfloat16 h = __float2bfloat16(f);
    short s; __builtin_memcpy(&s, &h, 2); return s;
}
__device__ __forceinline__ float bfl(unsigned u) {
    unsigned v = u << 16; float f; __builtin_memcpy(&f, &v, 4); return f;
}
__device__ __forceinline__ float bfh(unsigned u) {
    unsigned v = u & 0xffff0000u; float f; __builtin_memcpy(&f, &v, 4); return f;
}
__device__ __forceinline__ unsigned packbf(float a, float b) {
    return (unsigned)(unsigned short)f2bf(a) | ((unsigned)(unsigned short)f2bf(b) << 16);
}
__device__ __forceinline__ void gll16(const void* gsrc, void* ldst) {
    __builtin_amdgcn_global_load_lds(
        (const __attribute__((address_space(1))) unsigned int*)gsrc,
        (__attribute__((address_space(3))) unsigned int*)ldst, 16, 0, 0);
}

// ---------------------------------------------------------------------------
// K0: merged pre-pass — cvtx (bid<2048) + cvtw (bid>=2048). 3328 blocks.
__global__ __launch_bounds__(256) void k_cvt(const float* __restrict__ x,
                                             const float* __restrict__ wq,
                                             const float* __restrict__ wk,
                                             const float* __restrict__ wv,
                                             const float* __restrict__ pj,
                                             bf16* __restrict__ xT,
                                             bf16* __restrict__ Wbf,
                                             bf16* __restrict__ Pbf) {
    __shared__ short lds[64][72];
    const int bid = blockIdx.x;
    const int t   = threadIdx.x;

    if (bid < 2048) {   // ---- cvtx: x [b][512][4096] f32 -> xT [b][px][512] bf16
        const int px0 = (bid & 63) * 64;
        const int k0  = ((bid >> 6) & 7) * 64;
        const int b   = bid >> 9;

        const int pr = t & 15, rr = t >> 4;
#pragma unroll
        for (int it = 0; it < 4; ++it) {
            const int row = it * 16 + rr;
            f32x4 v = *(const f32x4*)(x + (size_t)(b * CIN + k0 + row) * NPIX + px0 + pr * 4);
#pragma unroll
            for (int i = 0; i < 4; ++i) lds[pr * 4 + i][row] = f2bf(v[i]);
        }
        __syncthreads();

        const int px = t >> 2, kc = t & 3;
        uint4 u0 = *(const uint4*)&lds[px][kc * 16];
        uint4 u1 = *(const uint4*)&lds[px][kc * 16 + 8];
        bf16* dst = xT + ((size_t)b * NPIX + px0 + px) * 512 + k0 + kc * 16;
        *(uint4*)dst = u0;
        *(uint4*)(dst + 8) = u1;
    } else {            // ---- cvtw: weights -> bf16
        const int e = ((bid - 2048) * 256 + t) * 4;
        const float* s; bf16* dst;
        if (e < 786432) {
            int o;
            if (e < 262144)      { s = wq; o = e; }
            else if (e < 524288) { s = wk; o = e - 262144; }
            else                 { s = wv; o = e - 524288; }
            f32x4 v = *(const f32x4*)(s + o);
            dst = Wbf + e;
            *(ushort2*)dst = make_ushort2((unsigned short)f2bf(v[0]), (unsigned short)f2bf(v[1]));
            *(ushort2*)(dst + 2) = make_ushort2((unsigned short)f2bf(v[2]), (unsigned short)f2bf(v[3]));
        } else {
            const int o = e - 786432;
            f32x4 v = *(const f32x4*)(pj + o);
            dst = Pbf + o;
            *(ushort2*)dst = make_ushort2((unsigned short)f2bf(v[0]), (unsigned short)f2bf(v[1]));
            *(ushort2*)(dst + 2) = make_ushort2((unsigned short)f2bf(v[2]), (unsigned short)f2bf(v[3]));
        }
    }
}

// ---------------------------------------------------------------------------
// MFMA GEMM v3 (gll16 both operands). (unchanged)
template<int KD, int MT, bool PROJ>
__global__ __launch_bounds__(256) void k_gemm3(
        const bf16* __restrict__ Xt,
        const bf16* __restrict__ Wb,
        bf16* __restrict__ Obf,
        const float* __restrict__ gm, const float* __restrict__ bt,
        const float* __restrict__ mu, const float* __restrict__ va,
        const float* __restrict__ resid, float* __restrict__ Of)
{
    constexpr int NT = KD / 32;
    constexpr int MS = MT / 32;
    constexpr int AG = MT / 64;
    __shared__ short Ald[2][MT * 32];
    __shared__ short Bld[2][128 * 32];

    const int t    = threadIdx.x;
    const int lane = t & 63;
    const int w    = t >> 6;
    const int wm   = w >> 1, wn = w & 1;
    const int n0   = blockIdx.x * 128;
    const int c0   = blockIdx.y * MT;
    const int b    = blockIdx.z;

    const bf16* abase = Wb + (size_t)(c0 + w * (MT / 4) + (lane >> 2)) * KD + (lane & 3) * 8;
    const bf16* bbase = Xt + ((size_t)b * NPIX + n0 + w * 32 + (lane >> 2)) * KD + (lane & 3) * 8;

    auto stage = [&](int s, int buf) {
#pragma unroll
        for (int q = 0; q < AG; ++q)
            gll16(abase + (size_t)q * 16 * KD + s * 32,
                  &Ald[buf][(w * (MT / 4) + q * 16) * 32]);
#pragma unroll
        for (int q = 0; q < 2; ++q)
            gll16(bbase + (size_t)q * 16 * KD + s * 32,
                  &Bld[buf][(w * 32 + q * 16) * 32]);
    };

    f32x4 acc[MS][4];
#pragma unroll
    for (int ms = 0; ms < MS; ++ms)
#pragma unroll
        for (int ns = 0; ns < 4; ++ns)
#pragma unroll
            for (int j = 0; j < 4; ++j) acc[ms][ns][j] = 0.f;

    stage(0, 0);
    __syncthreads();

    const int l15 = lane & 15, l4 = lane >> 4;
    for (int s = 0; s < NT; ++s) {
        const int cur = s & 1;
        if (s + 1 < NT) stage(s + 1, cur ^ 1);

        bf16x8 af[MS], bv[4];
#pragma unroll
        for (int ms = 0; ms < MS; ++ms)
            af[ms] = *(const bf16x8*)&Ald[cur][(wm * (MT / 2) + ms * 16 + l15) * 32 + l4 * 8];
#pragma unroll
        for (int ns = 0; ns < 4; ++ns)
            bv[ns] = *(const bf16x8*)&Bld[cur][(wn * 64 + ns * 16 + l15) * 32 + l4 * 8];
#pragma unroll
        for (int ms = 0; ms < MS; ++ms)
#pragma unroll
            for (int ns = 0; ns < 4; ++ns)
                acc[ms][ns] = __builtin_amdgcn_mfma_f32_16x16x32_bf16(
                    af[ms], bv[ns], acc[ms][ns], 0, 0, 0);

        __syncthreads();
    }

    if (!PROJ) {
#pragma unroll
        for (int ms = 0; ms < MS; ++ms) {
            const int crow = c0 + wm * (MT / 2) + ms * 16 + l4 * 4;
#pragma unroll
            for (int ns = 0; ns < 4; ++ns) {
                const int ncol = n0 + wn * 64 + ns * 16 + l15;
#pragma unroll
                for (int j = 0; j < 4; ++j) {
                    bf16 h; short sv = f2bf(acc[ms][ns][j]);
                    __builtin_memcpy(&h, &sv, 2);
                    Obf[((size_t)b * CALL + crow + j) * NPIX + ncol] = h;
                }
            }
        }
    } else {
#pragma unroll
        for (int ms = 0; ms < MS; ++ms) {
            const int crow = c0 + wm * (MT / 2) + ms * 16 + l4 * 4;
#pragma unroll
            for (int j = 0; j < 4; ++j) {
                const int o = crow + j;
                const float inv = gm[o] / sqrtf(va[o] + BN_EPS);
                const float sh  = bt[o] - mu[o] * inv;
#pragma unroll
                for (int ns = 0; ns < 4; ++ns) {
                    const int ncol = n0 + wn * 64 + ns * 16 + l15;
                    const size_t idx = ((size_t)b * 512 + o) * NPIX + ncol;
                    Of[idx] = acc[ms][ns][j] * inv + sh + resid[idx];
                }
            }
        }
    }
}

// ---------------------------------------------------------------------------
// Device bodies (unchanged logic).
#define DW_ICS 1608
#define DW_DCS 1032

__device__ __forceinline__ void dwpw_body(const float* __restrict__ dwk,
                                          const float* __restrict__ pwk,
                                          bf16* __restrict__ qkv_all,
                                          short* slds,
                                          int ytile, int g, int b) {
    const int t  = threadIdx.x;
    const int y0 = ytile * 16;

    const bf16* src = qkv_all + ((size_t)b * CALL + g * 8) * NPIX;
#pragma unroll
    for (int i = 0; i < 7; ++i) {
        const int v = i * 256 + t;
        if (v < 1600) {
            const int ch  = v / 200;
            const int rem = v % 200;
            const int row = rem / 10;
            const int seg = rem % 10;
            const int grow = y0 + row - 2;
            uint4 val = make_uint4(0u, 0u, 0u, 0u);
            if (seg >= 1 && seg <= 8 && grow >= 0 && grow < HW)
                val = *(const uint4*)(src + (size_t)ch * NPIX + grow * HW + (seg - 1) * 8);
            *(uint4*)&slds[ch * DW_ICS + row * 80 + seg * 8] = val;
        }
    }

    const int lane = t & 63;
    const int w    = t >> 6;
    const int xb   = lane & 7;
    const int ch   = lane >> 3;
    const int x0   = xb * 8;

    float kc[25];
    {
        const float* kp = dwk + (size_t)(g * 8 + ch) * 25;
#pragma unroll
        for (int i = 0; i < 25; ++i) kc[i] = kp[i];
    }
    __syncthreads();

    float A[5][12];
    const short* cb = &slds[ch * DW_ICS + x0];

    auto loadrow = [&](int L, float* f) {
        const short* rp = cb + L * 80;
        uint2 lo = *(const uint2*)(rp + 4);
        uint4 md = *(const uint4*)(rp + 8);
        uint2 hi = *(const uint2*)(rp + 16);
        f[0]  = bfl(lo.y); f[1]  = bfh(lo.y);
        f[2]  = bfl(md.x); f[3]  = bfh(md.x);
        f[4]  = bfl(md.y); f[5]  = bfh(md.y);
        f[6]  = bfl(md.z); f[7]  = bfh(md.z);
        f[8]  = bfl(md.w); f[9]  = bfh(md.w);
        f[10] = bfl(hi.x); f[11] = bfh(hi.x);
    };

    const int r0 = w * 4;
    loadrow(r0 + 0, A[0]);
    loadrow(r0 + 1, A[1]);
    loadrow(r0 + 2, A[2]);
    loadrow(r0 + 3, A[3]);

    uint4 pk[4];
#pragma unroll
    for (int ri = 0; ri < 4; ++ri) {
        loadrow(r0 + ri + 4, A[(ri + 4) % 5]);
        float acc[8];
#pragma unroll
        for (int i = 0; i < 8; ++i) acc[i] = 0.f;
#pragma unroll
        for (int dy = 0; dy < 5; ++dy) {
            const float* Ar = A[(ri + dy) % 5];
#pragma unroll
            for (int dx = 0; dx < 5; ++dx) {
                const float kv = kc[dy * 5 + dx];
#pragma unroll
                for (int i = 0; i < 8; ++i)
                    acc[i] += Ar[i + dx] * kv;
            }
        }
        pk[ri].x = packbf(acc[0], acc[1]);
        pk[ri].y = packbf(acc[2], acc[3]);
        pk[ri].z = packbf(acc[4], acc[5]);
        pk[ri].w = packbf(acc[6], acc[7]);
    }
    __syncthreads();

#pragma unroll
    for (int ri = 0; ri < 4; ++ri)
        *(uint4*)&slds[ch * DW_DCS + (r0 + ri) * 64 + x0] = pk[ri];
    __syncthreads();

    const float* pwb = pwk + (size_t)g * 64;
#pragma unroll
    for (int it = 0; it < 2; ++it) {
        const int p2 = (it * 256 + t) * 2;
        float v0[8], v1[8];
#pragma unroll
        for (int ci = 0; ci < 8; ++ci) {
            const unsigned u = *(const unsigned*)&slds[ci * DW_DCS + p2];
            v0[ci] = bfl(u); v1[ci] = bfh(u);
        }
        bf16* op = qkv_all + ((size_t)b * CALL + 1536 + g * 8) * NPIX + y0 * HW + p2;
#pragma unroll
        for (int o = 0; o < 8; ++o) {
            float s0 = 0.f, s1 = 0.f;
#pragma unroll
            for (int ci = 0; ci < 8; ++ci) {
                const float wv = pwb[o * 8 + ci];
                s0 += wv * v0[ci]; s1 += wv * v1[ci];
            }
            *(unsigned*)(op + (size_t)o * NPIX) = packbf(s0, s1);
        }
    }
}

__device__ __forceinline__ void scores_body(const bf16* __restrict__ qkv_all,
                                            float* __restrict__ part,
                                            int ns, int h, int b) {
    const int lane = threadIdx.x & 63;
    const bf16* base = qkv_all + ((size_t)b * CALL + h * 24) * NPIX;

    float acc[72];
#pragma unroll
    for (int i = 0; i < 72; ++i) acc[i] = 0.f;

    for (int it = 0; it < 4; ++it) {
        const int n = ns * 512 + it * 128 + lane * 2;
        const bf16* p = base + n;
        float k0[8], k1[8], v0[8], v1[8];
#pragma unroll
        for (int e = 0; e < 8; ++e) {
            const unsigned u = *(const unsigned*)&p[(size_t)(8 + e) * NPIX];
            k0[e] = fmaxf(bfl(u), 0.f); k1[e] = fmaxf(bfh(u), 0.f);
        }
#pragma unroll
        for (int d = 0; d < 8; ++d) {
            const unsigned u = *(const unsigned*)&p[(size_t)(16 + d) * NPIX];
            v0[d] = bfl(u); v1[d] = bfh(u);
        }
#pragma unroll
        for (int d = 0; d < 9; ++d) {
            const float vd0 = (d < 8) ? v0[d] : 1.f;
            const float vd1 = (d < 8) ? v1[d] : 1.f;
#pragma unroll
            for (int e = 0; e < 8; ++e)
                acc[d * 8 + e] += vd0 * k0[e] + vd1 * k1[e];
        }
    }

    const int bh = b * NHEAD + h;
#pragma unroll
    for (int i = 0; i < 72; ++i) {
        float v = acc[i];
        for (int off = 32; off; off >>= 1) v += __shfl_xor(v, off, 64);
        if (lane == 0) part[((size_t)bh * 72 + i) * 8 + ns] = v;
    }
}

__device__ __forceinline__ void att_body(const bf16* __restrict__ qkv_all,
                                         const float* __restrict__ part,
                                         bf16* __restrict__ attT,
                                         float* sc,
                                         int xt, int h, int b) {
    const int t  = threadIdx.x;
    const int bh = b * NHEAD + h;

    if (t < 72) {
        float s = 0.f;
#pragma unroll
        for (int nss = 0; nss < 8; ++nss) s += part[((size_t)bh * 72 + t) * 8 + nss];
        sc[t] = s;
    }
    __syncthreads();

    const int px = xt * 256 + t;
    const bf16* qb = qkv_all + ((size_t)b * CALL + h * 24) * NPIX + px;
    float q[8];
#pragma unroll
    for (int e = 0; e < 8; ++e)
        q[e] = fmaxf(__bfloat162float(qb[(size_t)e * NPIX]), 0.f);

    float num[9];
#pragma unroll
    for (int d = 0; d < 9; ++d) {
        float s = 0.f;
#pragma unroll
        for (int e = 0; e < 8; ++e) s += sc[d * 8 + e] * q[e];
        num[d] = s;
    }
    const float inv = 1.f / (num[8] + EPS_LITE);
    uint4 pk;
    pk.x = packbf(num[0] * inv, num[1] * inv);
    pk.y = packbf(num[2] * inv, num[3] * inv);
    pk.z = packbf(num[4] * inv, num[5] * inv);
    pk.w = packbf(num[6] * inv, num[7] * inv);
    *(uint4*)(attT + ((size_t)b * NPIX + px) * 1024 + h * 8) = pk;
}

// ---------------------------------------------------------------------------
// Fuse1: scores heads 0-63 (bid<512) + dwpw (bid>=512). 3584 blocks @256.
// NOTE: no min-waves arg — R9's (256,4) forced 64 VGPR and spilled acc[72].
__global__ __launch_bounds__(256) void k_fuse1(const float* __restrict__ dwk,
                                               const float* __restrict__ pwk,
                                               bf16* __restrict__ qkv_all,
                                               float* __restrict__ part) {
    __shared__ short slds[8 * DW_ICS];
    const int bid = blockIdx.x;
    if (bid < 512) {
        const int ns = bid & 7, hg = (bid >> 3) & 15, b = bid >> 7;
        const int h  = hg * 4 + (threadIdx.x >> 6);
        scores_body(qkv_all, part, ns, h, b);
    } else {
        const int db = bid - 512;
        const int ytile = db & 3, g = (db >> 2) % 192, b = db / 768;
        dwpw_body(dwk, pwk, qkv_all, slds, ytile, g, b);
    }
}

// Fuse2: scores heads 64-127 (bid<512) + att heads 0-63 (bid>=512). 4608 blocks.
__global__ __launch_bounds__(256) void k_fuse2(const bf16* __restrict__ qkv_all,
                                               float* __restrict__ part,
                                               bf16* __restrict__ attT) {
    __shared__ float sc[72];
    const int bid = blockIdx.x;
    if (bid < 512) {
        const int ns = bid & 7, hg = (bid >> 3) & 15, b = bid >> 7;
        const int h  = 64 + hg * 4 + (threadIdx.x >> 6);
        scores_body(qkv_all, part, ns, h, b);
    } else {
        const int ab = bid - 512;
        const int xt = ab & 15, h = (ab >> 4) & 63, b = ab >> 10;
        att_body(qkv_all, part, attT, sc, xt, h, b);
    }
}

// att heads 64-127. grid (16,64,4) @256.
__global__ __launch_bounds__(256) void k_att_hi(const bf16* __restrict__ qkv_all,
                                                const float* __restrict__ part,
                                                bf16* __restrict__ attT) {
    __shared__ float sc[72];
    att_body(qkv_all, part, attT, sc, blockIdx.x, blockIdx.y + 64, blockIdx.z);
}

// ---------------------------------------------------------------------------
extern "C" void kernel_launch(void* const* d_in, const int* in_sizes, int n_in,
                              void* d_out, int out_size, void* d_ws, size_t ws_size,
                              hipStream_t stream) {
    const float* x   = (const float*)d_in[0];
    const float* wq  = (const float*)d_in[1];
    const float* wk  = (const float*)d_in[2];
    const float* wv  = (const float*)d_in[3];
    const float* dwk = (const float*)d_in[4];
    const float* pwk = (const float*)d_in[5];
    const float* pj  = (const float*)d_in[6];
    const float* gm  = (const float*)d_in[7];
    const float* bt  = (const float*)d_in[8];
    const float* mu  = (const float*)d_in[9];
    const float* va  = (const float*)d_in[10];
    float* out = (float*)d_out;

    char* ws = (char*)d_ws;
    bf16*  qkv_all = (bf16*)(ws);
    bf16*  attT    = (bf16*)(ws + 100663296);
    bf16*  xT      = (bf16*)(ws + 100663296);   // aliases attT; dead before att writes
    float* part    = (float*)(ws + 134217728);
    bf16*  Wbf     = (bf16*)(ws + 135544832);
    bf16*  Pbf     = (bf16*)(ws + 137117696);

    k_cvt<<<dim3(3328), 256, 0, stream>>>(x, wq, wk, wv, pj, xT, Wbf, Pbf);
    // QKV: M=1536, K=512
    k_gemm3<512, 128, false><<<dim3(32, 12, BATCH), 256, 0, stream>>>(
        xT, Wbf, qkv_all, nullptr, nullptr, nullptr, nullptr, nullptr, nullptr);
    k_fuse1 <<<dim3(3584), 256, 0, stream>>>(dwk, pwk, qkv_all, part);
    k_fuse2 <<<dim3(4608), 256, 0, stream>>>(qkv_all, part, attT);
    k_att_hi<<<dim3(16, 64, BATCH), 256, 0, stream>>>(qkv_all, part, attT);
    // Proj: M=512, K=1024, + BN + residual
    k_gemm3<1024, 64, true><<<dim3(32, 8, BATCH), 256, 0, stream>>>(
        attT, Pbf, nullptr, gm, bt, mu, va, x, out);
}

// Round 11
// 166.801 us; speedup vs baseline: 1.3550x; 1.1057x over previous
//
#include <hip/hip_runtime.h>
#include <hip/hip_bf16.h>

typedef __hip_bfloat16 bf16;
typedef __attribute__((ext_vector_type(8))) short bf16x8;
typedef __attribute__((ext_vector_type(4))) float f32x4;
typedef __attribute__((ext_vector_type(2))) float f32v2;

#define BATCH 4
#define CIN   512
#define HW    64
#define NPIX  4096
#define CALL  3072
#define NHEAD 128
#define EPS_LITE 1e-15f
#define BN_EPS   1e-5f

// Workspace (bytes), total ~138.2 MiB:
//   qkv_all (bf16): 0         .. 100663296
//   attT/xT (bf16): 100663296 .. 134217728   (xT aliases attT; dead before att writes)
//   part    (f32) : 134217728 .. 135397376
//   Wbf     (bf16): 135544832 .. 137117696
//   Pbf     (bf16): 137117696 .. 138166272

__device__ __forceinline__ short f2bf(float f) {
    __hip_bfloat16 h = __float2bfloat16(f);
    short s; __builtin_memcpy(&s, &h, 2); return s;
}
__device__ __forceinline__ float bfl(unsigned u) {
    unsigned v = u << 16; float f; __builtin_memcpy(&f, &v, 4); return f;
}
__device__ __forceinline__ float bfh(unsigned u) {
    unsigned v = u & 0xffff0000u; float f; __builtin_memcpy(&f, &v, 4); return f;
}
__device__ __forceinline__ unsigned packbf(float a, float b) {
    return (unsigned)(unsigned short)f2bf(a) | ((unsigned)(unsigned short)f2bf(b) << 16);
}
__device__ __forceinline__ void gll16(const void* gsrc, void* ldst) {
    __builtin_amdgcn_global_load_lds(
        (const __attribute__((address_space(1))) unsigned int*)gsrc,
        (__attribute__((address_space(3))) unsigned int*)ldst, 16, 0, 0);
}

// ---------------------------------------------------------------------------
// K0: merged pre-pass — cvtx (bid<2048) + cvtw (bid>=2048). 3328 blocks.
__global__ __launch_bounds__(256) void k_cvt(const float* __restrict__ x,
                                             const float* __restrict__ wq,
                                             const float* __restrict__ wk,
                                             const float* __restrict__ wv,
                                             const float* __restrict__ pj,
                                             bf16* __restrict__ xT,
                                             bf16* __restrict__ Wbf,
                                             bf16* __restrict__ Pbf) {
    __shared__ short lds[64][72];
    const int bid = blockIdx.x;
    const int t   = threadIdx.x;

    if (bid < 2048) {
        const int px0 = (bid & 63) * 64;
        const int k0  = ((bid >> 6) & 7) * 64;
        const int b   = bid >> 9;

        const int pr = t & 15, rr = t >> 4;
#pragma unroll
        for (int it = 0; it < 4; ++it) {
            const int row = it * 16 + rr;
            f32x4 v = *(const f32x4*)(x + (size_t)(b * CIN + k0 + row) * NPIX + px0 + pr * 4);
#pragma unroll
            for (int i = 0; i < 4; ++i) lds[pr * 4 + i][row] = f2bf(v[i]);
        }
        __syncthreads();

        const int px = t >> 2, kc = t & 3;
        uint4 u0 = *(const uint4*)&lds[px][kc * 16];
        uint4 u1 = *(const uint4*)&lds[px][kc * 16 + 8];
        bf16* dst = xT + ((size_t)b * NPIX + px0 + px) * 512 + k0 + kc * 16;
        *(uint4*)dst = u0;
        *(uint4*)(dst + 8) = u1;
    } else {
        const int e = ((bid - 2048) * 256 + t) * 4;
        const float* s; bf16* dst;
        if (e < 786432) {
            int o;
            if (e < 262144)      { s = wq; o = e; }
            else if (e < 524288) { s = wk; o = e - 262144; }
            else                 { s = wv; o = e - 524288; }
            f32x4 v = *(const f32x4*)(s + o);
            dst = Wbf + e;
            *(ushort2*)dst = make_ushort2((unsigned short)f2bf(v[0]), (unsigned short)f2bf(v[1]));
            *(ushort2*)(dst + 2) = make_ushort2((unsigned short)f2bf(v[2]), (unsigned short)f2bf(v[3]));
        } else {
            const int o = e - 786432;
            f32x4 v = *(const f32x4*)(pj + o);
            dst = Pbf + o;
            *(ushort2*)dst = make_ushort2((unsigned short)f2bf(v[0]), (unsigned short)f2bf(v[1]));
            *(ushort2*)(dst + 2) = make_ushort2((unsigned short)f2bf(v[2]), (unsigned short)f2bf(v[3]));
        }
    }
}

// ---------------------------------------------------------------------------
// MFMA GEMM v3 (gll16 both operands). (unchanged)
template<int KD, int MT, bool PROJ>
__global__ __launch_bounds__(256) void k_gemm3(
        const bf16* __restrict__ Xt,
        const bf16* __restrict__ Wb,
        bf16* __restrict__ Obf,
        const float* __restrict__ gm, const float* __restrict__ bt,
        const float* __restrict__ mu, const float* __restrict__ va,
        const float* __restrict__ resid, float* __restrict__ Of)
{
    constexpr int NT = KD / 32;
    constexpr int MS = MT / 32;
    constexpr int AG = MT / 64;
    __shared__ short Ald[2][MT * 32];
    __shared__ short Bld[2][128 * 32];

    const int t    = threadIdx.x;
    const int lane = t & 63;
    const int w    = t >> 6;
    const int wm   = w >> 1, wn = w & 1;
    const int n0   = blockIdx.x * 128;
    const int c0   = blockIdx.y * MT;
    const int b    = blockIdx.z;

    const bf16* abase = Wb + (size_t)(c0 + w * (MT / 4) + (lane >> 2)) * KD + (lane & 3) * 8;
    const bf16* bbase = Xt + ((size_t)b * NPIX + n0 + w * 32 + (lane >> 2)) * KD + (lane & 3) * 8;

    auto stage = [&](int s, int buf) {
#pragma unroll
        for (int q = 0; q < AG; ++q)
            gll16(abase + (size_t)q * 16 * KD + s * 32,
                  &Ald[buf][(w * (MT / 4) + q * 16) * 32]);
#pragma unroll
        for (int q = 0; q < 2; ++q)
            gll16(bbase + (size_t)q * 16 * KD + s * 32,
                  &Bld[buf][(w * 32 + q * 16) * 32]);
    };

    f32x4 acc[MS][4];
#pragma unroll
    for (int ms = 0; ms < MS; ++ms)
#pragma unroll
        for (int ns = 0; ns < 4; ++ns)
#pragma unroll
            for (int j = 0; j < 4; ++j) acc[ms][ns][j] = 0.f;

    stage(0, 0);
    __syncthreads();

    const int l15 = lane & 15, l4 = lane >> 4;
    for (int s = 0; s < NT; ++s) {
        const int cur = s & 1;
        if (s + 1 < NT) stage(s + 1, cur ^ 1);

        bf16x8 af[MS], bv[4];
#pragma unroll
        for (int ms = 0; ms < MS; ++ms)
            af[ms] = *(const bf16x8*)&Ald[cur][(wm * (MT / 2) + ms * 16 + l15) * 32 + l4 * 8];
#pragma unroll
        for (int ns = 0; ns < 4; ++ns)
            bv[ns] = *(const bf16x8*)&Bld[cur][(wn * 64 + ns * 16 + l15) * 32 + l4 * 8];
#pragma unroll
        for (int ms = 0; ms < MS; ++ms)
#pragma unroll
            for (int ns = 0; ns < 4; ++ns)
                acc[ms][ns] = __builtin_amdgcn_mfma_f32_16x16x32_bf16(
                    af[ms], bv[ns], acc[ms][ns], 0, 0, 0);

        __syncthreads();
    }

    if (!PROJ) {
#pragma unroll
        for (int ms = 0; ms < MS; ++ms) {
            const int crow = c0 + wm * (MT / 2) + ms * 16 + l4 * 4;
#pragma unroll
            for (int ns = 0; ns < 4; ++ns) {
                const int ncol = n0 + wn * 64 + ns * 16 + l15;
#pragma unroll
                for (int j = 0; j < 4; ++j) {
                    bf16 h; short sv = f2bf(acc[ms][ns][j]);
                    __builtin_memcpy(&h, &sv, 2);
                    Obf[((size_t)b * CALL + crow + j) * NPIX + ncol] = h;
                }
            }
        }
    } else {
#pragma unroll
        for (int ms = 0; ms < MS; ++ms) {
            const int crow = c0 + wm * (MT / 2) + ms * 16 + l4 * 4;
#pragma unroll
            for (int j = 0; j < 4; ++j) {
                const int o = crow + j;
                const float inv = gm[o] / sqrtf(va[o] + BN_EPS);
                const float sh  = bt[o] - mu[o] * inv;
#pragma unroll
                for (int ns = 0; ns < 4; ++ns) {
                    const int ncol = n0 + wn * 64 + ns * 16 + l15;
                    const size_t idx = ((size_t)b * 512 + o) * NPIX + ncol;
                    Of[idx] = acc[ms][ns][j] * inv + sh + resid[idx];
                }
            }
        }
    }
}

// ---------------------------------------------------------------------------
// K2 v6: depthwise 5x5 + grouped 1x1. 256 threads, TWO 16-row tiles per block
// with async-stage pipelining (T14): tile1's global loads issue before tile0's
// compute, hiding HBM latency under the dw FMA phase. Single reused LDS buffer.
// grid (2, 192, 4) = 1536 blocks.
#define DW_ICS 1608   // input ch stride (shorts)
#define DW_DCS 1032   // dw    ch stride (shorts)
__global__ __launch_bounds__(256) void k_dwpw(const float* __restrict__ dwk,
                                              const float* __restrict__ pwk,
                                              bf16* __restrict__ qkv_all) {
    __shared__ short slds[8 * DW_ICS];   // 25728 B; in-area reused as dw-area

    const int t   = threadIdx.x;
    const int g   = blockIdx.y;
    const int b   = blockIdx.z;
    const int yt0 = blockIdx.x * 2;

    const bf16* src = qkv_all + ((size_t)b * CALL + g * 8) * NPIX;

    const int lane = t & 63;
    const int w    = t >> 6;
    const int xb   = lane & 7;
    const int ch   = lane >> 3;
    const int x0   = xb * 8;

    // staging role (constant per thread)
    const int sv   = t;                      // v = i*256 + t
    auto tload = [&](int ytile, uint4* r) {
        const int y0 = ytile * 16;
#pragma unroll
        for (int i = 0; i < 7; ++i) {
            const int v = i * 256 + sv;
            uint4 val = make_uint4(0u, 0u, 0u, 0u);
            if (v < 1600) {
                const int c  = v / 200;
                const int rm = v % 200;
                const int rw = rm / 10;
                const int sg = rm % 10;
                const int grow = y0 + rw - 2;
                if (sg >= 1 && sg <= 8 && grow >= 0 && grow < HW)
                    val = *(const uint4*)(src + (size_t)c * NPIX + grow * HW + (sg - 1) * 8);
            }
            r[i] = val;
        }
    };
    auto twrite = [&](const uint4* r) {
#pragma unroll
        for (int i = 0; i < 7; ++i) {
            const int v = i * 256 + sv;
            if (v < 1600) {
                const int c  = v / 200;
                const int rm = v % 200;
                const int rw = rm / 10;
                const int sg = rm % 10;
                *(uint4*)&slds[c * DW_ICS + rw * 80 + sg * 8] = r[i];
            }
        }
    };

    float kc[25];
    {
        const float* kp = dwk + (size_t)(g * 8 + ch) * 25;
#pragma unroll
        for (int i = 0; i < 25; ++i) kc[i] = kp[i];
    }

    auto compute_tile = [&](int ytile) {
        const int y0 = ytile * 16;
        float A[5][12];
        const short* cb = &slds[ch * DW_ICS + x0];

        auto loadrow = [&](int L, float* f) {
            const short* rp = cb + L * 80;
            uint2 lo = *(const uint2*)(rp + 4);
            uint4 md = *(const uint4*)(rp + 8);
            uint2 hi = *(const uint2*)(rp + 16);
            f[0]  = bfl(lo.y); f[1]  = bfh(lo.y);
            f[2]  = bfl(md.x); f[3]  = bfh(md.x);
            f[4]  = bfl(md.y); f[5]  = bfh(md.y);
            f[6]  = bfl(md.z); f[7]  = bfh(md.z);
            f[8]  = bfl(md.w); f[9]  = bfh(md.w);
            f[10] = bfl(hi.x); f[11] = bfh(hi.x);
        };

        const int rr0 = w * 4;
        loadrow(rr0 + 0, A[0]);
        loadrow(rr0 + 1, A[1]);
        loadrow(rr0 + 2, A[2]);
        loadrow(rr0 + 3, A[3]);

        uint4 pk[4];
#pragma unroll
        for (int ri = 0; ri < 4; ++ri) {
            loadrow(rr0 + ri + 4, A[(ri + 4) % 5]);
            float acc[8];
#pragma unroll
            for (int i = 0; i < 8; ++i) acc[i] = 0.f;
#pragma unroll
            for (int dy = 0; dy < 5; ++dy) {
                const float* Ar = A[(ri + dy) % 5];
#pragma unroll
                for (int dx = 0; dx < 5; ++dx) {
                    const float kv = kc[dy * 5 + dx];
#pragma unroll
                    for (int i = 0; i < 8; ++i)
                        acc[i] += Ar[i + dx] * kv;
                }
            }
            pk[ri].x = packbf(acc[0], acc[1]);
            pk[ri].y = packbf(acc[2], acc[3]);
            pk[ri].z = packbf(acc[4], acc[5]);
            pk[ri].w = packbf(acc[6], acc[7]);
        }
        __syncthreads();                      // all input reads done

#pragma unroll
        for (int ri = 0; ri < 4; ++ri)
            *(uint4*)&slds[ch * DW_DCS + (rr0 + ri) * 64 + x0] = pk[ri];
        __syncthreads();

        // pointwise 8->8, pixel-pairs packed as f32v2
        const float* pwb = pwk + (size_t)g * 64;
#pragma unroll
        for (int it2 = 0; it2 < 2; ++it2) {
            const int p2 = (it2 * 256 + t) * 2;
            f32v2 v2[8];
#pragma unroll
            for (int ci = 0; ci < 8; ++ci) {
                const unsigned u = *(const unsigned*)&slds[ci * DW_DCS + p2];
                v2[ci][0] = bfl(u); v2[ci][1] = bfh(u);
            }
            bf16* op = qkv_all + ((size_t)b * CALL + 1536 + g * 8) * NPIX + y0 * HW + p2;
#pragma unroll
            for (int o = 0; o < 8; ++o) {
                f32v2 s2 = {0.f, 0.f};
#pragma unroll
                for (int ci = 0; ci < 8; ++ci)
                    s2 += pwb[o * 8 + ci] * v2[ci];
                *(unsigned*)(op + (size_t)o * NPIX) = packbf(s2[0], s2[1]);
            }
        }
    };

    uint4 rA[7], rB[7];
    tload(yt0, rA);
    twrite(rA);
    __syncthreads();
    tload(yt0 + 1, rB);        // in flight under tile0's dw compute
    compute_tile(yt0);
    __syncthreads();           // tile0 LDS reads done before overwrite
    twrite(rB);
    __syncthreads();
    compute_tile(yt0 + 1);
}

// ---------------------------------------------------------------------------
// K3: scores partials. (R8 form) grid (8,128,4), block 64.
__global__ __launch_bounds__(64) void k_scores(const bf16* __restrict__ qkv_all,
                                               float* __restrict__ part) {
    const int lane = threadIdx.x;
    const int h = blockIdx.y;
    const int b = blockIdx.z;
    const bf16* base = qkv_all + ((size_t)b * CALL + h * 24) * NPIX;

    float acc[72];
#pragma unroll
    for (int i = 0; i < 72; ++i) acc[i] = 0.f;

    for (int it = 0; it < 4; ++it) {
        const int n = blockIdx.x * 512 + it * 128 + lane * 2;
        const bf16* p = base + n;
        float k0[8], k1[8], v0[8], v1[8];
#pragma unroll
        for (int e = 0; e < 8; ++e) {
            const unsigned u = *(const unsigned*)&p[(size_t)(8 + e) * NPIX];
            k0[e] = fmaxf(bfl(u), 0.f); k1[e] = fmaxf(bfh(u), 0.f);
        }
#pragma unroll
        for (int d = 0; d < 8; ++d) {
            const unsigned u = *(const unsigned*)&p[(size_t)(16 + d) * NPIX];
            v0[d] = bfl(u); v1[d] = bfh(u);
        }
#pragma unroll
        for (int d = 0; d < 9; ++d) {
            const float vd0 = (d < 8) ? v0[d] : 1.f;
            const float vd1 = (d < 8) ? v1[d] : 1.f;
#pragma unroll
            for (int e = 0; e < 8; ++e)
                acc[d * 8 + e] += vd0 * k0[e] + vd1 * k1[e];
        }
    }

    const int bh = b * NHEAD + h;
#pragma unroll
    for (int i = 0; i < 72; ++i) {
        float v = acc[i];
        for (int off = 32; off; off >>= 1) v += __shfl_xor(v, off, 64);
        if (lane == 0) part[((size_t)bh * 72 + i) * 8 + blockIdx.x] = v;
    }
}

// ---------------------------------------------------------------------------
// K4: att with fused partial-reduction + transposed output. (R8 form)
__global__ __launch_bounds__(256) void k_att3(const bf16* __restrict__ qkv_all,
                                              const float* __restrict__ part,
                                              bf16* __restrict__ attT) {
    __shared__ float sc[72];
    const int t  = threadIdx.x;
    const int h  = blockIdx.y;
    const int b  = blockIdx.z;
    const int bh = b * NHEAD + h;

    if (t < 72) {
        float s = 0.f;
#pragma unroll
        for (int ns = 0; ns < 8; ++ns) s += part[((size_t)bh * 72 + t) * 8 + ns];
        sc[t] = s;
    }
    __syncthreads();

    const int px = blockIdx.x * 256 + t;
    const bf16* qb = qkv_all + ((size_t)b * CALL + h * 24) * NPIX + px;
    float q[8];
#pragma unroll
    for (int e = 0; e < 8; ++e)
        q[e] = fmaxf(__bfloat162float(qb[(size_t)e * NPIX]), 0.f);

    float num[9];
#pragma unroll
    for (int d = 0; d < 9; ++d) {
        float s = 0.f;
#pragma unroll
        for (int e = 0; e < 8; ++e) s += sc[d * 8 + e] * q[e];
        num[d] = s;
    }
    const float inv = 1.f / (num[8] + EPS_LITE);
    uint4 pk;
    pk.x = packbf(num[0] * inv, num[1] * inv);
    pk.y = packbf(num[2] * inv, num[3] * inv);
    pk.z = packbf(num[4] * inv, num[5] * inv);
    pk.w = packbf(num[6] * inv, num[7] * inv);
    *(uint4*)(attT + ((size_t)b * NPIX + px) * 1024 + h * 8) = pk;
}

// ---------------------------------------------------------------------------
extern "C" void kernel_launch(void* const* d_in, const int* in_sizes, int n_in,
                              void* d_out, int out_size, void* d_ws, size_t ws_size,
                              hipStream_t stream) {
    const float* x   = (const float*)d_in[0];
    const float* wq  = (const float*)d_in[1];
    const float* wk  = (const float*)d_in[2];
    const float* wv  = (const float*)d_in[3];
    const float* dwk = (const float*)d_in[4];
    const float* pwk = (const float*)d_in[5];
    const float* pj  = (const float*)d_in[6];
    const float* gm  = (const float*)d_in[7];
    const float* bt  = (const float*)d_in[8];
    const float* mu  = (const float*)d_in[9];
    const float* va  = (const float*)d_in[10];
    float* out = (float*)d_out;

    char* ws = (char*)d_ws;
    bf16*  qkv_all = (bf16*)(ws);
    bf16*  attT    = (bf16*)(ws + 100663296);
    bf16*  xT      = (bf16*)(ws + 100663296);   // aliases attT; dead before att writes
    float* part    = (float*)(ws + 134217728);
    bf16*  Wbf     = (bf16*)(ws + 135544832);
    bf16*  Pbf     = (bf16*)(ws + 137117696);

    k_cvt<<<dim3(3328), 256, 0, stream>>>(x, wq, wk, wv, pj, xT, Wbf, Pbf);
    // QKV: M=1536, K=512
    k_gemm3<512, 128, false><<<dim3(32, 12, BATCH), 256, 0, stream>>>(
        xT, Wbf, qkv_all, nullptr, nullptr, nullptr, nullptr, nullptr, nullptr);
    k_dwpw  <<<dim3( 2, 192, BATCH), 256, 0, stream>>>(dwk, pwk, qkv_all);
    k_scores<<<dim3( 8, 128, BATCH),  64, 0, stream>>>(qkv_all, part);
    k_att3  <<<dim3(16, 128, BATCH), 256, 0, stream>>>(qkv_all, part, attT);
    // Proj: M=512, K=1024, + BN + residual
    k_gemm3<1024, 64, true><<<dim3(32, 8, BATCH), 256, 0, stream>>>(
        attT, Pbf, nullptr, gm, bt, mu, va, x, out);
}